// Round 7
// baseline (420.943 us; speedup 1.0000x reference)
//
#include <hip/hip_runtime.h>
#include <math.h>

#define HCDIM 256   // H*C
#define HEADS 8
#define CH 32
#define NEG 0.2f

typedef __attribute__((ext_vector_type(2))) float f32x2;
typedef __attribute__((ext_vector_type(8))) short bf16x8;
typedef __attribute__((ext_vector_type(4))) float f32x4;

__device__ __forceinline__ float4 ld4(const float* p){ return *reinterpret_cast<const float4*>(p); }
__device__ __forceinline__ void st4(float* p, float a, float b, float c, float d){
    float4 v; v.x=a; v.y=b; v.z=c; v.w=d; *reinterpret_cast<float4*>(p)=v;
}
__device__ __forceinline__ unsigned short f2bf(float f){
    union { float f; unsigned u; } x; x.f = f;
    unsigned r = x.u + 0x7fff + ((x.u >> 16) & 1);   // RNE
    return (unsigned short)(r >> 16);
}
__device__ __forceinline__ float bf2f(unsigned short u){
    union { unsigned u; float f; } x; x.u = (unsigned)u << 16; return x.f;
}

// ---- packed fp32 (VOP3P) helpers ----
__device__ __forceinline__ f32x2 pk_fma(f32x2 a, f32x2 b, f32x2 c){
    f32x2 d;
    asm("v_pk_fma_f32 %0, %1, %2, %3" : "=v"(d) : "v"(a), "v"(b), "v"(c));
    return d;
}
__device__ __forceinline__ f32x2 pk_add(f32x2 a, f32x2 b){
    f32x2 d;
    asm("v_pk_add_f32 %0, %1, %2" : "=v"(d) : "v"(a), "v"(b));
    return d;
}
__device__ __forceinline__ f32x2 pk_mul(f32x2 a, f32x2 b){
    f32x2 d;
    asm("v_pk_mul_f32 %0, %1, %2" : "=v"(d) : "v"(a), "v"(b));
    return d;
}
// unpack 2 bf16 (packed in u32) -> f32x2 {lo, hi}
__device__ __forceinline__ f32x2 unpk_bf(unsigned u){
    f32x2 r;
    r[0] = __uint_as_float(u << 16);
    r[1] = __uint_as_float(u & 0xffff0000u);
    return r;
}

// ---------- preprocessing ----------
__global__ void k_init(int* deg, float* lsum, int* cursor, int n){
    int i = blockIdx.x*blockDim.x + threadIdx.x;
    if (i < n){ deg[i]=0; lsum[i]=0.f; cursor[i]=0; }
}

__global__ void k_count(const int* __restrict__ dst, const float* __restrict__ eattr,
                        int* deg, float* lsum, int E){
    int e = blockIdx.x*blockDim.x + threadIdx.x;
    if (e < E){
        int d = dst[e];
        atomicAdd(&deg[d], 1);
        atomicAdd(&lsum[d], eattr[e]);
    }
}

// single-block scan: offs[0]=0, offs[i+1]=sum deg[0..i]
__global__ void k_scan(const int* __restrict__ deg, int* __restrict__ offs, int n){
    __shared__ int wsum[16];
    __shared__ int carry;
    int tid = threadIdx.x;            // 1024 threads
    if (tid == 0) carry = 0;
    __syncthreads();
    int lane = tid & 63, wid = tid >> 6;
    for (int base = 0; base < n; base += 1024){
        int i = base + tid;
        int x = (i < n) ? deg[i] : 0;
        #pragma unroll
        for (int o = 1; o < 64; o <<= 1){
            int y = __shfl_up(x, o);
            if (lane >= o) x += y;
        }
        if (lane == 63) wsum[wid] = x;
        __syncthreads();
        if (tid == 0){
            int run = 0;
            for (int w = 0; w < 16; w++){ run += wsum[w]; wsum[w] = run; }
        }
        __syncthreads();
        int pre = (wid > 0 ? wsum[wid-1] : 0) + carry;
        int incl = x + pre;
        if (i < n) offs[i+1] = incl;
        __syncthreads();
        if (tid == 1023) carry = incl;
        __syncthreads();
    }
    if (tid == 0) offs[0] = 0;
}

__global__ void k_loopattr(const int* deg, const float* lsum, float* lattr, int n){
    int i = blockIdx.x*blockDim.x + threadIdx.x;
    if (i < n) lattr[i] = lsum[i] / fmaxf((float)deg[i], 1.0f);
}

__global__ void k_scatter(const int* __restrict__ src, const int* __restrict__ dst,
                          const float* __restrict__ eattr, const int* __restrict__ offs,
                          int* cursor, int2* csr, int E){
    int e = blockIdx.x*blockDim.x + threadIdx.x;
    if (e < E){
        int d = dst[e];
        int pos = offs[d] + atomicAdd(&cursor[d], 1);
        int2 pk; pk.x = src[e]; pk.y = __float_as_int(eattr[e]);
        csr[pos] = pk;
    }
}

// ---------- fp32 dual GEMM (layer 0 only, din=3), bf16 outputs ----------
__global__ __launch_bounds__(256) void k_dualgemm(
        const float* __restrict__ h, int din,
        const float* __restrict__ Wl, const float* __restrict__ bl,
        const float* __restrict__ Wr, const float* __restrict__ br,
        unsigned short* __restrict__ xl, unsigned short* __restrict__ xr, int n)
{
    const int ROWS = 16;
    __shared__ float hs[ROWS * HCDIM];
    int row0 = blockIdx.x * ROWS;
    int j = threadIdx.x;

    for (int idx = threadIdx.x; idx < ROWS*din; idx += 256){
        int r = idx / din, k = idx - r*din;
        int row = row0 + r;
        hs[r*din + k] = (row < n) ? h[(size_t)row*din + k] : 0.f;
    }
    __syncthreads();

    float accl[ROWS], accr[ROWS];
    float blj = bl[j], brj = br[j];
    #pragma unroll
    for (int r = 0; r < ROWS; r++){ accl[r] = blj; accr[r] = brj; }

    for (int k = 0; k < din; k++){
        float wl = Wl[k*HCDIM + j], wr = Wr[k*HCDIM + j];
        #pragma unroll
        for (int r = 0; r < ROWS; r++){
            float hv = hs[r*din + k];
            accl[r] += hv*wl;
            accr[r] += hv*wr;
        }
    }
    #pragma unroll
    for (int r = 0; r < ROWS; r++){
        int row = row0 + r;
        if (row < n){
            xl[(size_t)row*HCDIM + j] = f2bf(accl[r]);
            xr[(size_t)row*HCDIM + j] = f2bf(accr[r]);
        }
    }
}

// ---------- weight convert+transpose for BOTH mfma layers in one launch ----------
__global__ __launch_bounds__(256) void k_cvtw2(
        const float* __restrict__ Wl1, const float* __restrict__ Wr1,
        const float* __restrict__ Wl2, const float* __restrict__ Wr2,
        unsigned short* __restrict__ Wt1, unsigned short* __restrict__ Wt2)
{
    int idx = blockIdx.x*256 + threadIdx.x;     // [0, 2*512*256)
    int half = idx >> 17;                       // 512*256 = 131072 = 1<<17
    int j = idx & 131071;
    int nout = j >> 8, k = j & 255;
    const float* Wl = half ? Wl2 : Wl1;
    const float* Wr = half ? Wr2 : Wr1;
    float v = (nout < 256) ? Wl[k*HCDIM + nout] : Wr[k*HCDIM + (nout - 256)];
    (half ? Wt2 : Wt1)[j] = f2bf(v);
}

// ---------- bf16 MFMA GEMM, A-resident: [xl | xr] = h @ [Wl | Wr] + [bl | br] ----------
// A (128 rows x 256 k) staged ONCE in LDS; loop 4 N-chunks of 128 in-kernel.
#define BM 128
#define LDA2 264   // padded A stride (bf16): 528B rows -> 2-way-free bank pattern
#define LDB2 40    // padded B tile stride

__global__ __launch_bounds__(256) void k_mfma_gemm(
        const unsigned short* __restrict__ h,
        const unsigned short* __restrict__ Wt,
        const float* __restrict__ bl, const float* __restrict__ br,
        unsigned short* __restrict__ xl, unsigned short* __restrict__ xr, int n)
{
    __shared__ unsigned short As[BM*LDA2];      // 67.6 KB
    __shared__ unsigned short Bs[128*LDB2];     // 10.25 KB
    int tid = threadIdx.x;
    int row0 = blockIdx.x * BM;
    int l = tid & 63, w = tid >> 6;
    int wm = (w >> 1) * 64, wn = (w & 1) * 64;

    // stage A fully (16 x uint4 per thread)
    #pragma unroll
    for (int it = 0; it < 16; ++it){
        int flat = it*2048 + tid*8;
        int r = flat >> 8, c = flat & 255;
        int grow = row0 + r;
        uint4 v;
        if (grow < n) v = *reinterpret_cast<const uint4*>(h + (size_t)grow*HCDIM + c);
        else { v.x=v.y=v.z=v.w=0u; }
        *reinterpret_cast<uint4*>(&As[r*LDA2 + c]) = v;
    }

    int srow = tid >> 1, skoff = (tid & 1) * 16;

    for (int c4 = 0; c4 < 4; ++c4){
        int col0 = c4 * 128;
        f32x4 acc[4][4] = {};
        // prefetch first B tile
        const uint4* bp = reinterpret_cast<const uint4*>(Wt + (size_t)(col0+srow)*HCDIM + skoff);
        uint4 bv0 = bp[0], bv1 = bp[1];
        for (int kt = 0; kt < 8; ++kt){
            __syncthreads();   // prior reads of Bs (and A-stage on first pass) done
            *reinterpret_cast<uint4*>(&Bs[srow*LDB2 + skoff])     = bv0;
            *reinterpret_cast<uint4*>(&Bs[srow*LDB2 + skoff + 8]) = bv1;
            if (kt < 7){
                const uint4* bp2 = reinterpret_cast<const uint4*>(
                    Wt + (size_t)(col0+srow)*HCDIM + (kt+1)*32 + skoff);
                bv0 = bp2[0]; bv1 = bp2[1];
            }
            __syncthreads();

            bf16x8 af[4], bfr[4];
            int kb = kt*32 + ((l >> 4)*8);
            #pragma unroll
            for (int m = 0; m < 4; m++)
                af[m] = *reinterpret_cast<const bf16x8*>(&As[(wm + m*16 + (l & 15))*LDA2 + kb]);
            #pragma unroll
            for (int nn = 0; nn < 4; nn++)
                bfr[nn] = *reinterpret_cast<const bf16x8*>(&Bs[(wn + nn*16 + (l & 15))*LDB2 + ((l >> 4)*8)]);
            #pragma unroll
            for (int m = 0; m < 4; m++)
                #pragma unroll
                for (int nn = 0; nn < 4; nn++)
                    acc[m][nn] = __builtin_amdgcn_mfma_f32_16x16x32_bf16(af[m], bfr[nn], acc[m][nn], 0, 0, 0);
        }

        unsigned short* dstp; const float* biasp; int cbase;
        if (c4 < 2){ dstp = xl; biasp = bl; cbase = col0; }
        else       { dstp = xr; biasp = br; cbase = col0 - 256; }

        #pragma unroll
        for (int nn = 0; nn < 4; nn++){
            int gc = cbase + wn + nn*16 + (l & 15);
            float bb = biasp[gc];
            #pragma unroll
            for (int m = 0; m < 4; m++){
                int r0 = row0 + wm + m*16 + ((l >> 4) * 4);
                #pragma unroll
                for (int v = 0; v < 4; v++){
                    int rr = r0 + v;
                    if (rr < n) dstp[(size_t)rr*HCDIM + gc] = f2bf(acc[m][nn][v] + bb);
                }
            }
        }
    }
}

// ---------- fused GATv2 edge kernel: TWO waves per dst node, packed-f32 math ----------
__global__ __launch_bounds__(256) void k_gat(
        const unsigned short* __restrict__ xl, const unsigned short* __restrict__ xr,
        const int2* __restrict__ csr,
        const int* __restrict__ offs, const float* __restrict__ lattr,
        const float* __restrict__ We, const float* __restrict__ att,
        const float* __restrict__ bias,
        unsigned short* __restrict__ hout_bf, float* __restrict__ hout_f,
        int n, int concat)
{
    __shared__ float smg[4][64][6];
    int wid  = threadIdx.x >> 6;     // 0..3
    int lane = threadIdx.x & 63;
    int pair = wid >> 1;             // node slot in block
    int half = wid & 1;              // 0: even csr positions + self loop; 1: odd
    int v = blockIdx.x*2 + pair;
    bool valid = (v < n);

    const int cb = lane*4;           // head=lane/8, ch=(lane%8)*4
    float4 We4  = ld4(We + cb);
    float4 att4 = ld4(att + cb);
    f32x2 We01 = {We4.x, We4.y}, We23 = {We4.z, We4.w};
    f32x2 at01 = {att4.x, att4.y}, at23 = {att4.z, att4.w};
    f32x2 cNEG = {NEG, NEG};
    f32x2 xr01 = {0.f, 0.f}, xr23 = {0.f, 0.f};
    int pbeg=0, pend=0;
    float la = 0.f;
    if (valid){
        uint2 xr4u = *reinterpret_cast<const uint2*>(xr + (size_t)v*HCDIM + cb);
        xr01 = unpk_bf(xr4u.x); xr23 = unpk_bf(xr4u.y);
        pbeg = offs[v]; pend = offs[v+1];
        la = lattr[v];
    }

    float mh = -INFINITY, s = 0.f;
    f32x2 a01 = {0.f, 0.f}, a23 = {0.f, 0.f};

    auto edge_step = [&](uint2 u, float ea){
        f32x2 x01 = unpk_bf(u.x), x23 = unpk_bf(u.y);
        f32x2 ea2 = {ea, ea};
        f32x2 t01 = pk_add(x01, pk_fma(ea2, We01, xr01));
        f32x2 t23 = pk_add(x23, pk_fma(ea2, We23, xr23));
        f32x2 m01 = pk_mul(t01, cNEG);
        f32x2 m23 = pk_mul(t23, cNEG);
        t01[0] = fmaxf(t01[0], m01[0]); t01[1] = fmaxf(t01[1], m01[1]);
        t23[0] = fmaxf(t23[0], m23[0]); t23[1] = fmaxf(t23[1], m23[1]);
        f32x2 pp = pk_fma(t23, at23, pk_mul(t01, at01));
        float part = pp[0] + pp[1];
        part += __shfl_xor(part, 1);
        part += __shfl_xor(part, 2);
        part += __shfl_xor(part, 4);     // logit uniform within head's 8 lanes
        float d = part - mh;             // +inf on first edge
        if (__any(d > 20.f)){            // exact online rescale (rare after first)
            float nm = fmaxf(mh, part);
            float sc = __expf(mh - nm);
            float ww = __expf(part - nm);
            s  = s*sc + ww;
            f32x2 sc2 = {sc, sc}, w2 = {ww, ww};
            a01 = pk_fma(w2, x01, pk_mul(a01, sc2));
            a23 = pk_fma(w2, x23, pk_mul(a23, sc2));
            mh = nm;
        } else {                          // fast path: deferred max
            float ww = __expf(d);
            s += ww;
            f32x2 w2 = {ww, ww};
            a01 = pk_fma(w2, x01, a01);
            a23 = pk_fma(w2, x23, a23);
        }
    };

    if (half == 0 && valid){
        uint2 xv4 = *reinterpret_cast<const uint2*>(xl + (size_t)v*HCDIM + cb);
        edge_step(xv4, la);            // self loop
    }

    // pipelined stride-2 edge loop
    int p = pbeg + half;
    int2 eA, eB; uint2 xuA;
    if (p < pend){
        eA = csr[p];
        xuA = *reinterpret_cast<const uint2*>(xl + ((size_t)eA.x << 8) + cb);
        if (p + 2 < pend) eB = csr[p + 2];
    }
    for (; p < pend; p += 2){
        uint2 cur = xuA;
        float ea = __int_as_float(eA.y);
        if (p + 2 < pend){
            xuA = *reinterpret_cast<const uint2*>(xl + ((size_t)eB.x << 8) + cb);
            eA = eB;
            if (p + 4 < pend) eB = csr[p + 4];
        }
        edge_step(cur, ea);
    }

    // merge the two halves' online-softmax states
    smg[wid][lane][0] = mh; smg[wid][lane][1] = s;
    smg[wid][lane][2] = a01[0]; smg[wid][lane][3] = a01[1];
    smg[wid][lane][4] = a23[0]; smg[wid][lane][5] = a23[1];
    __syncthreads();
    if (half != 0 || !valid) return;

    float m2  = smg[wid+1][lane][0];
    float s2  = smg[wid+1][lane][1];
    float a2x = smg[wid+1][lane][2];
    float a2y = smg[wid+1][lane][3];
    float a2z = smg[wid+1][lane][4];
    float a2w = smg[wid+1][lane][5];
    float M  = fmaxf(mh, m2);          // mh finite (self loop) => M finite
    float c1 = __expf(mh - M);
    float c2 = __expf(m2 - M);         // exp(-inf)=0 when half1 empty
    s = s*c1 + s2*c2;
    float ax = a01[0]*c1 + a2x*c2;
    float ay = a01[1]*c1 + a2y*c2;
    float az = a23[0]*c1 + a2z*c2;
    float aw = a23[1]*c1 + a2w*c2;

    float inv = 1.f / s;
    if (concat){
        float4 b4 = ld4(bias + cb);
        ushort4 o;
        o.x = f2bf(fmaxf(ax*inv + b4.x, 0.f));
        o.y = f2bf(fmaxf(ay*inv + b4.y, 0.f));
        o.z = f2bf(fmaxf(az*inv + b4.z, 0.f));
        o.w = f2bf(fmaxf(aw*inv + b4.w, 0.f));
        *reinterpret_cast<ushort4*>(hout_bf + (size_t)v*HCDIM + cb) = o;
    } else {
        float ox = ax*inv, oy = ay*inv, oz = az*inv, ow = aw*inv;
        #pragma unroll
        for (int o = 8; o < 64; o <<= 1){
            ox += __shfl_xor(ox, o); oy += __shfl_xor(oy, o);
            oz += __shfl_xor(oz, o); ow += __shfl_xor(ow, o);
        }
        int c0 = (lane & 7)*4;
        float4 b4 = ld4(bias + c0);
        ox = fmaxf(ox*0.125f + b4.x, 0.f);
        oy = fmaxf(oy*0.125f + b4.y, 0.f);
        oz = fmaxf(oz*0.125f + b4.z, 0.f);
        ow = fmaxf(ow*0.125f + b4.w, 0.f);
        if (lane < 8) st4(hout_f + (size_t)v*CH + c0, ox, oy, oz, ow);
    }
}

// ---------- fused heads stage 1: node log-softmax out + Pe = h @ ehW1 (bf16) ----------
__global__ __launch_bounds__(256) void k_heads(
        const float* __restrict__ hf,
        const float* __restrict__ nW1, const float* __restrict__ nb1,
        const float* __restrict__ nW2, const float* __restrict__ nb2,
        const float* __restrict__ eW1,
        float* __restrict__ out, unsigned short* __restrict__ Pe, int count)
{
    __shared__ float sh[8][CH];
    int g = threadIdx.x >> 5;
    int t = threadIdx.x & 31;
    int i = blockIdx.x*8 + g;
    sh[g][t] = (i < count) ? hf[(size_t)i*CH + t] : 0.f;
    __syncthreads();
    float z = nb1[t];
    float pe = 0.f;
    #pragma unroll
    for (int k = 0; k < CH; k++){
        float hk = sh[g][k];
        z  = fmaf(hk, nW1[k*CH + t], z);
        pe = fmaf(hk, eW1[k*CH + t], pe);
    }
    if (i < count) Pe[(size_t)i*CH + t] = f2bf(pe);
    z = fmaxf(z, 0.f);
    float r0 = z * nW2[t*2 + 0];
    float r1 = z * nW2[t*2 + 1];
    #pragma unroll
    for (int o = 1; o < 32; o <<= 1){
        r0 += __shfl_xor(r0, o);
        r1 += __shfl_xor(r1, o);
    }
    if (t == 0 && i < count){
        float z0 = r0 + nb2[0], z1 = r1 + nb2[1];
        float mm = fmaxf(z0, z1);
        float lse = mm + __logf(__expf(z0 - mm) + __expf(z1 - mm));
        out[(size_t)i*2 + 0] = z0 - lse;
        out[(size_t)i*2 + 1] = z1 - lse;
    }
}

// ---------- edge head finisher: 8 lanes per edge, bf16 P gathers ----------
__global__ __launch_bounds__(256) void k_edgefin(
        const unsigned short* __restrict__ P,
        const int* __restrict__ src, const int* __restrict__ dst,
        const float* __restrict__ b1, const float* __restrict__ W2,
        const float* __restrict__ b2, float* __restrict__ out, int E)
{
    int gt = blockIdx.x*256 + threadIdx.x;
    int e = gt >> 3, sub = gt & 7;
    if (e >= E) return;
    int s = src[e], d = dst[e];
    int c0 = sub*4;
    ushort4 us = *reinterpret_cast<const ushort4*>(P + (size_t)s*CH + c0);
    ushort4 ud = *reinterpret_cast<const ushort4*>(P + (size_t)d*CH + c0);
    float4 bb = ld4(b1 + c0);
    float zx = fmaxf(bf2f(us.x) + bf2f(ud.x) + bb.x, 0.f);
    float zy = fmaxf(bf2f(us.y) + bf2f(ud.y) + bb.y, 0.f);
    float zz = fmaxf(bf2f(us.z) + bf2f(ud.z) + bb.z, 0.f);
    float zw = fmaxf(bf2f(us.w) + bf2f(ud.w) + bb.w, 0.f);
    float r0 = zx*W2[(c0+0)*2] + zy*W2[(c0+1)*2] + zz*W2[(c0+2)*2] + zw*W2[(c0+3)*2];
    float r1 = zx*W2[(c0+0)*2+1] + zy*W2[(c0+1)*2+1] + zz*W2[(c0+2)*2+1] + zw*W2[(c0+3)*2+1];
    #pragma unroll
    for (int o = 1; o < 8; o <<= 1){
        r0 += __shfl_xor(r0, o);
        r1 += __shfl_xor(r1, o);
    }
    if (sub == 0){
        float z0 = r0 + b2[0], z1 = r1 + b2[1];
        float mm = fmaxf(z0, z1);
        float lse = mm + __logf(__expf(z0 - mm) + __expf(z1 - mm));
        float2 o2; o2.x = z0 - lse; o2.y = z1 - lse;
        *reinterpret_cast<float2*>(out + (size_t)e*2) = o2;
    }
}

extern "C" void kernel_launch(void* const* d_in, const int* in_sizes, int n_in,
                              void* d_out, int out_size, void* d_ws, size_t ws_size,
                              hipStream_t stream)
{
    const float* x     = (const float*)d_in[0];
    const int*   ei    = (const int*)d_in[1];
    const float* eattr = (const float*)d_in[2];
    int N = in_sizes[0] / 3;
    int E = in_sizes[2];
    const int* src0 = ei;
    const int* dst0 = ei + E;

    const float *Wl[3], *bl[3], *Wr[3], *br[3], *We[3], *att[3], *bias[3];
    for (int l = 0; l < 3; l++){
        int b = 3 + l*7;
        Wl[l]   = (const float*)d_in[b+0];
        bl[l]   = (const float*)d_in[b+1];
        Wr[l]   = (const float*)d_in[b+2];
        br[l]   = (const float*)d_in[b+3];
        We[l]   = (const float*)d_in[b+4];
        att[l]  = (const float*)d_in[b+5];
        bias[l] = (const float*)d_in[b+6];
    }
    const float* nhW1 = (const float*)d_in[24];
    const float* nhb1 = (const float*)d_in[25];
    const float* nhW2 = (const float*)d_in[26];
    const float* nhb2 = (const float*)d_in[27];
    const float* ehW1 = (const float*)d_in[28];
    const float* ehb1 = (const float*)d_in[29];
    const float* ehW2 = (const float*)d_in[30];
    const float* ehb2 = (const float*)d_in[31];

    char* ws = (char*)d_ws;
    auto alloc = [&](size_t bytes) -> char* {
        char* p = ws;
        ws += (bytes + 255) & ~(size_t)255;
        return p;
    };
    unsigned short* Hb  = (unsigned short*)alloc((size_t)N*HCDIM*2);  // layers 0/1 output
    float* H0f          = (float*)alloc((size_t)N*CH*4);              // layer 2 output
    unsigned short* XL  = (unsigned short*)alloc((size_t)N*HCDIM*2);
    unsigned short* XR  = (unsigned short*)alloc((size_t)N*HCDIM*2);
    int*   deg      = (int*)alloc((size_t)N*4);
    float* lsum     = (float*)alloc((size_t)N*4);
    float* lattr    = (float*)alloc((size_t)N*4);
    int*   offs     = (int*)alloc((size_t)(N+1)*4);
    int*   cursor   = (int*)alloc((size_t)N*4);
    int2*  csr      = (int2*)alloc((size_t)E*8);
    unsigned short* Wt1 = (unsigned short*)alloc((size_t)512*HCDIM*2);
    unsigned short* Wt2 = (unsigned short*)alloc((size_t)512*HCDIM*2);
    unsigned short* Pe  = (unsigned short*)alloc((size_t)N*CH*2);

    // preprocessing (+ both weight conversions upfront)
    k_init<<<(N+255)/256, 256, 0, stream>>>(deg, lsum, cursor, N);
    k_count<<<(E+255)/256, 256, 0, stream>>>(dst0, eattr, deg, lsum, E);
    k_scan<<<1, 1024, 0, stream>>>(deg, offs, N);
    k_loopattr<<<(N+255)/256, 256, 0, stream>>>(deg, lsum, lattr, N);
    k_scatter<<<(E+255)/256, 256, 0, stream>>>(src0, dst0, eattr, offs, cursor, csr, E);
    k_cvtw2<<<1024, 256, 0, stream>>>(Wl[1], Wr[1], Wl[2], Wr[2], Wt1, Wt2);

    int gat_grid  = (N + 1) / 2;     // 2 nodes per block, 2 waves per node
    int gemm_grid = (N + BM - 1) / BM;

    // layer 0 (din=3, fp32 vector GEMM -> bf16 xl/xr)
    k_dualgemm<<<(N+15)/16, 256, 0, stream>>>(x, 3, Wl[0], bl[0], Wr[0], br[0], XL, XR, N);
    k_gat<<<gat_grid, 256, 0, stream>>>(XL, XR, csr, offs, lattr,
                                        We[0], att[0], bias[0], Hb, nullptr, N, 1);
    // layer 1 (din=256, bf16 MFMA, A-resident)
    k_mfma_gemm<<<gemm_grid, 256, 0, stream>>>(Hb, Wt1, bl[1], br[1], XL, XR, N);
    k_gat<<<gat_grid, 256, 0, stream>>>(XL, XR, csr, offs, lattr,
                                        We[1], att[1], bias[1], Hb, nullptr, N, 1);
    // layer 2 (din=256, bf16 MFMA, concat=false -> f32 N x 32)
    k_mfma_gemm<<<gemm_grid, 256, 0, stream>>>(Hb, Wt2, bl[2], br[2], XL, XR, N);
    k_gat<<<gat_grid, 256, 0, stream>>>(XL, XR, csr, offs, lattr,
                                        We[2], att[2], bias[2], nullptr, H0f, N, 0);

    // fused node head + edge-P precompute, then tiny per-edge finisher
    float* out_node = (float*)d_out;
    float* out_edge = out_node + (size_t)N*2;
    k_heads<<<(N+7)/8, 256, 0, stream>>>(H0f, nhW1, nhb1, nhW2, nhb2, ehW1,
                                         out_node, Pe, N);
    k_edgefin<<<((size_t)E*8 + 255)/256, 256, 0, stream>>>(Pe, src0, dst0,
                                                           ehb1, ehW2, ehb2, out_edge, E);
}

// Round 8
// 341.867 us; speedup vs baseline: 1.2313x; 1.2313x over previous
//
#include <hip/hip_runtime.h>
#include <math.h>

#define HCDIM 256   // H*C
#define HEADS 8
#define CH 32
#define NEG 0.2f

typedef __attribute__((ext_vector_type(8))) short bf16x8;
typedef __attribute__((ext_vector_type(4))) float f32x4;

__device__ __forceinline__ float4 ld4(const float* p){ return *reinterpret_cast<const float4*>(p); }
__device__ __forceinline__ void st4(float* p, float a, float b, float c, float d){
    float4 v; v.x=a; v.y=b; v.z=c; v.w=d; *reinterpret_cast<float4*>(p)=v;
}
__device__ __forceinline__ unsigned short f2bf(float f){
    union { float f; unsigned u; } x; x.f = f;
    unsigned r = x.u + 0x7fff + ((x.u >> 16) & 1);   // RNE
    return (unsigned short)(r >> 16);
}
__device__ __forceinline__ float bf2f(unsigned short u){
    union { unsigned u; float f; } x; x.u = (unsigned)u << 16; return x.f;
}

// ---------- preprocessing ----------
__global__ void k_init(int* deg, float* lsum, int* cursor, int n){
    int i = blockIdx.x*blockDim.x + threadIdx.x;
    if (i < n){ deg[i]=0; lsum[i]=0.f; cursor[i]=0; }
}

__global__ void k_count(const int* __restrict__ dst, const float* __restrict__ eattr,
                        int* deg, float* lsum, int E){
    int e = blockIdx.x*blockDim.x + threadIdx.x;
    if (e < E){
        int d = dst[e];
        atomicAdd(&deg[d], 1);
        atomicAdd(&lsum[d], eattr[e]);
    }
}

// single-block scan: offs[0]=0, offs[i+1]=sum deg[0..i]
__global__ void k_scan(const int* __restrict__ deg, int* __restrict__ offs, int n){
    __shared__ int wsum[16];
    __shared__ int carry;
    int tid = threadIdx.x;            // 1024 threads
    if (tid == 0) carry = 0;
    __syncthreads();
    int lane = tid & 63, wid = tid >> 6;
    for (int base = 0; base < n; base += 1024){
        int i = base + tid;
        int x = (i < n) ? deg[i] : 0;
        #pragma unroll
        for (int o = 1; o < 64; o <<= 1){
            int y = __shfl_up(x, o);
            if (lane >= o) x += y;
        }
        if (lane == 63) wsum[wid] = x;
        __syncthreads();
        if (tid == 0){
            int run = 0;
            for (int w = 0; w < 16; w++){ run += wsum[w]; wsum[w] = run; }
        }
        __syncthreads();
        int pre = (wid > 0 ? wsum[wid-1] : 0) + carry;
        int incl = x + pre;
        if (i < n) offs[i+1] = incl;
        __syncthreads();
        if (tid == 1023) carry = incl;
        __syncthreads();
    }
    if (tid == 0) offs[0] = 0;
}

__global__ void k_loopattr(const int* deg, const float* lsum, float* lattr, int n){
    int i = blockIdx.x*blockDim.x + threadIdx.x;
    if (i < n) lattr[i] = lsum[i] / fmaxf((float)deg[i], 1.0f);
}

__global__ void k_scatter(const int* __restrict__ src, const int* __restrict__ dst,
                          const float* __restrict__ eattr, const int* __restrict__ offs,
                          int* cursor, int2* csr, int E){
    int e = blockIdx.x*blockDim.x + threadIdx.x;
    if (e < E){
        int d = dst[e];
        int pos = offs[d] + atomicAdd(&cursor[d], 1);
        int2 pk; pk.x = src[e]; pk.y = __float_as_int(eattr[e]);
        csr[pos] = pk;
    }
}

// ---------- fp32 dual GEMM (layer 0 only, din=3), bf16 outputs ----------
__global__ __launch_bounds__(256) void k_dualgemm(
        const float* __restrict__ h, int din,
        const float* __restrict__ Wl, const float* __restrict__ bl,
        const float* __restrict__ Wr, const float* __restrict__ br,
        unsigned short* __restrict__ xl, unsigned short* __restrict__ xr, int n)
{
    const int ROWS = 16;
    __shared__ float hs[ROWS * HCDIM];
    int row0 = blockIdx.x * ROWS;
    int j = threadIdx.x;

    for (int idx = threadIdx.x; idx < ROWS*din; idx += 256){
        int r = idx / din, k = idx - r*din;
        int row = row0 + r;
        hs[r*din + k] = (row < n) ? h[(size_t)row*din + k] : 0.f;
    }
    __syncthreads();

    float accl[ROWS], accr[ROWS];
    float blj = bl[j], brj = br[j];
    #pragma unroll
    for (int r = 0; r < ROWS; r++){ accl[r] = blj; accr[r] = brj; }

    for (int k = 0; k < din; k++){
        float wl = Wl[k*HCDIM + j], wr = Wr[k*HCDIM + j];
        #pragma unroll
        for (int r = 0; r < ROWS; r++){
            float hv = hs[r*din + k];
            accl[r] += hv*wl;
            accr[r] += hv*wr;
        }
    }
    #pragma unroll
    for (int r = 0; r < ROWS; r++){
        int row = row0 + r;
        if (row < n){
            xl[(size_t)row*HCDIM + j] = f2bf(accl[r]);
            xr[(size_t)row*HCDIM + j] = f2bf(accr[r]);
        }
    }
}

// ---------- weight convert+transpose for BOTH mfma layers in one launch ----------
__global__ __launch_bounds__(256) void k_cvtw2(
        const float* __restrict__ Wl1, const float* __restrict__ Wr1,
        const float* __restrict__ Wl2, const float* __restrict__ Wr2,
        unsigned short* __restrict__ Wt1, unsigned short* __restrict__ Wt2)
{
    int idx = blockIdx.x*256 + threadIdx.x;     // [0, 2*512*256)
    int half = idx >> 17;                       // 512*256 = 131072 = 1<<17
    int j = idx & 131071;
    int nout = j >> 8, k = j & 255;
    const float* Wl = half ? Wl2 : Wl1;
    const float* Wr = half ? Wr2 : Wr1;
    float v = (nout < 256) ? Wl[k*HCDIM + nout] : Wr[k*HCDIM + (nout - 256)];
    (half ? Wt2 : Wt1)[j] = f2bf(v);
}

// ---------- bf16 MFMA GEMM: [xl | xr] = h @ [Wl | Wr] + [bl | br] ----------
// A = h [n][256] bf16 ; B = Wt [512][256] bf16 n-major; bf16 outputs
#define BM 128
#define BN 128
#define BK 32
#define LDK 40   // padded LDS stride (bf16 elems)

__global__ __launch_bounds__(256) void k_mfma_gemm(
        const unsigned short* __restrict__ h,
        const unsigned short* __restrict__ Wt,
        const float* __restrict__ bl, const float* __restrict__ br,
        unsigned short* __restrict__ xl, unsigned short* __restrict__ xr, int n)
{
    __shared__ unsigned short As[BM*LDK];
    __shared__ unsigned short Bs[BN*LDK];
    int tid = threadIdx.x;
    int row0 = blockIdx.x * BM;
    int col0 = blockIdx.y * BN;      // 0,128,256,384 over [Wl|Wr]

    int l = tid & 63, w = tid >> 6;
    int wm = (w >> 1) * 64, wn = (w & 1) * 64;

    f32x4 acc[4][4] = {};

    int srow = tid >> 1;
    int skoff = (tid & 1) * 16;

    for (int kt = 0; kt < 8; ++kt){
        int kb = kt * BK;
        uint4 av0, av1;
        int grow = row0 + srow;
        if (grow < n){
            const uint4* ap = reinterpret_cast<const uint4*>(h + (size_t)grow*HCDIM + kb + skoff);
            av0 = ap[0]; av1 = ap[1];
        } else {
            av0.x=av0.y=av0.z=av0.w=0u; av1 = av0;
        }
        const uint4* bp = reinterpret_cast<const uint4*>(Wt + (size_t)(col0+srow)*HCDIM + kb + skoff);
        uint4 bv0 = bp[0], bv1 = bp[1];

        __syncthreads();   // previous iteration's LDS reads complete

        *reinterpret_cast<uint4*>(&As[srow*LDK + skoff])     = av0;
        *reinterpret_cast<uint4*>(&As[srow*LDK + skoff + 8]) = av1;
        *reinterpret_cast<uint4*>(&Bs[srow*LDK + skoff])     = bv0;
        *reinterpret_cast<uint4*>(&Bs[srow*LDK + skoff + 8]) = bv1;

        __syncthreads();

        bf16x8 af[4], bfr[4];
        #pragma unroll
        for (int m = 0; m < 4; m++)
            af[m] = *reinterpret_cast<const bf16x8*>(&As[(wm + m*16 + (l & 15))*LDK + ((l >> 4)*8)]);
        #pragma unroll
        for (int nn = 0; nn < 4; nn++)
            bfr[nn] = *reinterpret_cast<const bf16x8*>(&Bs[(wn + nn*16 + (l & 15))*LDK + ((l >> 4)*8)]);
        #pragma unroll
        for (int m = 0; m < 4; m++)
            #pragma unroll
            for (int nn = 0; nn < 4; nn++)
                acc[m][nn] = __builtin_amdgcn_mfma_f32_16x16x32_bf16(af[m], bfr[nn], acc[m][nn], 0, 0, 0);
    }

    unsigned short* dstp; const float* biasp; int cbase;
    if (col0 < 256){ dstp = xl; biasp = bl; cbase = col0; }
    else           { dstp = xr; biasp = br; cbase = col0 - 256; }

    #pragma unroll
    for (int nn = 0; nn < 4; nn++){
        int gc = cbase + wn + nn*16 + (l & 15);
        float bb = biasp[gc];
        #pragma unroll
        for (int m = 0; m < 4; m++){
            int r0 = row0 + wm + m*16 + ((l >> 4) * 4);
            #pragma unroll
            for (int v = 0; v < 4; v++){
                int rr = r0 + v;
                if (rr < n) dstp[(size_t)rr*HCDIM + gc] = f2bf(acc[m][nn][v] + bb);
            }
        }
    }
}

// ---------- fused GATv2 edge kernel: TWO waves per dst node (even/odd edges) ----------
// defer-max online softmax (scalar math — R6-proven config)
__global__ __launch_bounds__(256) void k_gat(
        const unsigned short* __restrict__ xl, const unsigned short* __restrict__ xr,
        const int2* __restrict__ csr,
        const int* __restrict__ offs, const float* __restrict__ lattr,
        const float* __restrict__ We, const float* __restrict__ att,
        const float* __restrict__ bias,
        unsigned short* __restrict__ hout_bf, float* __restrict__ hout_f,
        int n, int concat)
{
    __shared__ float smg[4][64][6];
    int wid  = threadIdx.x >> 6;     // 0..3
    int lane = threadIdx.x & 63;
    int pair = wid >> 1;             // node slot in block
    int half = wid & 1;              // 0: even csr positions + self loop; 1: odd
    int v = blockIdx.x*2 + pair;
    bool valid = (v < n);

    const int cb = lane*4;           // head=lane/8, ch=(lane%8)*4
    float4 We4  = ld4(We + cb);
    float4 att4 = ld4(att + cb);
    float xrx=0,xry=0,xrz=0,xrw=0;
    int pbeg=0, pend=0;
    float la = 0.f;
    if (valid){
        ushort4 xr4u = *reinterpret_cast<const ushort4*>(xr + (size_t)v*HCDIM + cb);
        xrx = bf2f(xr4u.x); xry = bf2f(xr4u.y); xrz = bf2f(xr4u.z); xrw = bf2f(xr4u.w);
        pbeg = offs[v]; pend = offs[v+1];
        la = lattr[v];
    }

    float mh = -INFINITY, s = 0.f;
    float ax = 0.f, ay = 0.f, az = 0.f, aw = 0.f;

    auto edge_step = [&](ushort4 xu4, float ea){
        float xux = bf2f(xu4.x), xuy = bf2f(xu4.y), xuz = bf2f(xu4.z), xuw = bf2f(xu4.w);
        float tx = xux + fmaf(ea, We4.x, xrx);
        float ty = xuy + fmaf(ea, We4.y, xry);
        float tz = xuz + fmaf(ea, We4.z, xrz);
        float tw = xuw + fmaf(ea, We4.w, xrw);
        tx = fmaxf(tx, NEG*tx);          // leaky relu, slope<1
        ty = fmaxf(ty, NEG*ty);
        tz = fmaxf(tz, NEG*tz);
        tw = fmaxf(tw, NEG*tw);
        float part = tx*att4.x + ty*att4.y + tz*att4.z + tw*att4.w;
        part += __shfl_xor(part, 1);
        part += __shfl_xor(part, 2);
        part += __shfl_xor(part, 4);     // logit uniform within head's 8 lanes
        float d = part - mh;             // +inf on first edge
        if (__any(d > 20.f)){            // slow path: exact online rescale
            float nm = fmaxf(mh, part);
            float sc = __expf(mh - nm);  // exp(-inf)=0 on first edge
            float w  = __expf(part - nm);
            s  = s*sc + w;
            ax = ax*sc + w*xux;
            ay = ay*sc + w*xuy;
            az = az*sc + w*xuz;
            aw = aw*sc + w*xuw;
            mh = nm;
        } else {                          // fast path: deferred max
            float w = __expf(d);
            s += w;
            ax = fmaf(w, xux, ax);
            ay = fmaf(w, xuy, ay);
            az = fmaf(w, xuz, az);
            aw = fmaf(w, xuw, aw);
        }
    };

    if (half == 0 && valid){
        ushort4 xv4 = *reinterpret_cast<const ushort4*>(xl + (size_t)v*HCDIM + cb);
        edge_step(xv4, la);            // self loop
    }

    // pipelined stride-2 edge loop: eA = current entry, eB = next entry (dist 2),
    // xuA = current gather (dist 1)
    int p = pbeg + half;
    int2 eA, eB; ushort4 xuA;
    if (p < pend){
        eA = csr[p];
        xuA = *reinterpret_cast<const ushort4*>(xl + ((size_t)eA.x << 8) + cb);
        if (p + 2 < pend) eB = csr[p + 2];
    }
    for (; p < pend; p += 2){
        ushort4 cur = xuA;
        float ea = __int_as_float(eA.y);
        if (p + 2 < pend){
            xuA = *reinterpret_cast<const ushort4*>(xl + ((size_t)eB.x << 8) + cb);
            eA = eB;
            if (p + 4 < pend) eB = csr[p + 4];
        }
        edge_step(cur, ea);
    }

    // merge the two halves' online-softmax states
    smg[wid][lane][0] = mh; smg[wid][lane][1] = s;
    smg[wid][lane][2] = ax; smg[wid][lane][3] = ay;
    smg[wid][lane][4] = az; smg[wid][lane][5] = aw;
    __syncthreads();
    if (half != 0 || !valid) return;

    float m2  = smg[wid+1][lane][0];
    float s2  = smg[wid+1][lane][1];
    float a2x = smg[wid+1][lane][2];
    float a2y = smg[wid+1][lane][3];
    float a2z = smg[wid+1][lane][4];
    float a2w = smg[wid+1][lane][5];
    float M  = fmaxf(mh, m2);          // mh finite (self loop) => M finite
    float c1 = __expf(mh - M);
    float c2 = __expf(m2 - M);         // exp(-inf)=0 when half1 empty
    s  = s*c1 + s2*c2;
    ax = ax*c1 + a2x*c2;
    ay = ay*c1 + a2y*c2;
    az = az*c1 + a2z*c2;
    aw = aw*c1 + a2w*c2;

    float inv = 1.f / s;
    if (concat){
        float4 b4 = ld4(bias + cb);
        ushort4 o;
        o.x = f2bf(fmaxf(ax*inv + b4.x, 0.f));
        o.y = f2bf(fmaxf(ay*inv + b4.y, 0.f));
        o.z = f2bf(fmaxf(az*inv + b4.z, 0.f));
        o.w = f2bf(fmaxf(aw*inv + b4.w, 0.f));
        *reinterpret_cast<ushort4*>(hout_bf + (size_t)v*HCDIM + cb) = o;
    } else {
        float ox = ax*inv, oy = ay*inv, oz = az*inv, ow = aw*inv;
        #pragma unroll
        for (int o = 8; o < 64; o <<= 1){
            ox += __shfl_xor(ox, o); oy += __shfl_xor(oy, o);
            oz += __shfl_xor(oz, o); ow += __shfl_xor(ow, o);
        }
        int c0 = (lane & 7)*4;
        float4 b4 = ld4(bias + c0);
        ox = fmaxf(ox*0.125f + b4.x, 0.f);
        oy = fmaxf(oy*0.125f + b4.y, 0.f);
        oz = fmaxf(oz*0.125f + b4.z, 0.f);
        ow = fmaxf(ow*0.125f + b4.w, 0.f);
        if (lane < 8) st4(hout_f + (size_t)v*CH + c0, ox, oy, oz, ow);
    }
}

// ---------- fused heads stage 1: node log-softmax out + Pe = h @ ehW1 (bf16) ----------
__global__ __launch_bounds__(256) void k_heads(
        const float* __restrict__ hf,
        const float* __restrict__ nW1, const float* __restrict__ nb1,
        const float* __restrict__ nW2, const float* __restrict__ nb2,
        const float* __restrict__ eW1,
        float* __restrict__ out, unsigned short* __restrict__ Pe, int count)
{
    __shared__ float sh[8][CH];
    int g = threadIdx.x >> 5;
    int t = threadIdx.x & 31;
    int i = blockIdx.x*8 + g;
    sh[g][t] = (i < count) ? hf[(size_t)i*CH + t] : 0.f;
    __syncthreads();
    float z = nb1[t];
    float pe = 0.f;
    #pragma unroll
    for (int k = 0; k < CH; k++){
        float hk = sh[g][k];
        z  = fmaf(hk, nW1[k*CH + t], z);
        pe = fmaf(hk, eW1[k*CH + t], pe);
    }
    if (i < count) Pe[(size_t)i*CH + t] = f2bf(pe);
    z = fmaxf(z, 0.f);
    float r0 = z * nW2[t*2 + 0];
    float r1 = z * nW2[t*2 + 1];
    #pragma unroll
    for (int o = 1; o < 32; o <<= 1){
        r0 += __shfl_xor(r0, o);
        r1 += __shfl_xor(r1, o);
    }
    if (t == 0 && i < count){
        float z0 = r0 + nb2[0], z1 = r1 + nb2[1];
        float mm = fmaxf(z0, z1);
        float lse = mm + __logf(__expf(z0 - mm) + __expf(z1 - mm));
        out[(size_t)i*2 + 0] = z0 - lse;
        out[(size_t)i*2 + 1] = z1 - lse;
    }
}

// ---------- edge head finisher: 8 lanes per edge, bf16 P gathers ----------
__global__ __launch_bounds__(256) void k_edgefin(
        const unsigned short* __restrict__ P,
        const int* __restrict__ src, const int* __restrict__ dst,
        const float* __restrict__ b1, const float* __restrict__ W2,
        const float* __restrict__ b2, float* __restrict__ out, int E)
{
    int gt = blockIdx.x*256 + threadIdx.x;
    int e = gt >> 3, sub = gt & 7;
    if (e >= E) return;
    int s = src[e], d = dst[e];
    int c0 = sub*4;
    ushort4 us = *reinterpret_cast<const ushort4*>(P + (size_t)s*CH + c0);
    ushort4 ud = *reinterpret_cast<const ushort4*>(P + (size_t)d*CH + c0);
    float4 bb = ld4(b1 + c0);
    float zx = fmaxf(bf2f(us.x) + bf2f(ud.x) + bb.x, 0.f);
    float zy = fmaxf(bf2f(us.y) + bf2f(ud.y) + bb.y, 0.f);
    float zz = fmaxf(bf2f(us.z) + bf2f(ud.z) + bb.z, 0.f);
    float zw = fmaxf(bf2f(us.w) + bf2f(ud.w) + bb.w, 0.f);
    float r0 = zx*W2[(c0+0)*2] + zy*W2[(c0+1)*2] + zz*W2[(c0+2)*2] + zw*W2[(c0+3)*2];
    float r1 = zx*W2[(c0+0)*2+1] + zy*W2[(c0+1)*2+1] + zz*W2[(c0+2)*2+1] + zw*W2[(c0+3)*2+1];
    #pragma unroll
    for (int o = 1; o < 8; o <<= 1){
        r0 += __shfl_xor(r0, o);
        r1 += __shfl_xor(r1, o);
    }
    if (sub == 0){
        float z0 = r0 + b2[0], z1 = r1 + b2[1];
        float mm = fmaxf(z0, z1);
        float lse = mm + __logf(__expf(z0 - mm) + __expf(z1 - mm));
        float2 o2; o2.x = z0 - lse; o2.y = z1 - lse;
        *reinterpret_cast<float2*>(out + (size_t)e*2) = o2;
    }
}

extern "C" void kernel_launch(void* const* d_in, const int* in_sizes, int n_in,
                              void* d_out, int out_size, void* d_ws, size_t ws_size,
                              hipStream_t stream)
{
    const float* x     = (const float*)d_in[0];
    const int*   ei    = (const int*)d_in[1];
    const float* eattr = (const float*)d_in[2];
    int N = in_sizes[0] / 3;
    int E = in_sizes[2];
    const int* src0 = ei;
    const int* dst0 = ei + E;

    const float *Wl[3], *bl[3], *Wr[3], *br[3], *We[3], *att[3], *bias[3];
    for (int l = 0; l < 3; l++){
        int b = 3 + l*7;
        Wl[l]   = (const float*)d_in[b+0];
        bl[l]   = (const float*)d_in[b+1];
        Wr[l]   = (const float*)d_in[b+2];
        br[l]   = (const float*)d_in[b+3];
        We[l]   = (const float*)d_in[b+4];
        att[l]  = (const float*)d_in[b+5];
        bias[l] = (const float*)d_in[b+6];
    }
    const float* nhW1 = (const float*)d_in[24];
    const float* nhb1 = (const float*)d_in[25];
    const float* nhW2 = (const float*)d_in[26];
    const float* nhb2 = (const float*)d_in[27];
    const float* ehW1 = (const float*)d_in[28];
    const float* ehb1 = (const float*)d_in[29];
    const float* ehW2 = (const float*)d_in[30];
    const float* ehb2 = (const float*)d_in[31];

    char* ws = (char*)d_ws;
    auto alloc = [&](size_t bytes) -> char* {
        char* p = ws;
        ws += (bytes + 255) & ~(size_t)255;
        return p;
    };
    unsigned short* Hb  = (unsigned short*)alloc((size_t)N*HCDIM*2);  // layers 0/1 output
    float* H0f          = (float*)alloc((size_t)N*CH*4);              // layer 2 output
    unsigned short* XL  = (unsigned short*)alloc((size_t)N*HCDIM*2);
    unsigned short* XR  = (unsigned short*)alloc((size_t)N*HCDIM*2);
    int*   deg      = (int*)alloc((size_t)N*4);
    float* lsum     = (float*)alloc((size_t)N*4);
    float* lattr    = (float*)alloc((size_t)N*4);
    int*   offs     = (int*)alloc((size_t)(N+1)*4);
    int*   cursor   = (int*)alloc((size_t)N*4);
    int2*  csr      = (int2*)alloc((size_t)E*8);
    unsigned short* Wt1 = (unsigned short*)alloc((size_t)512*HCDIM*2);
    unsigned short* Wt2 = (unsigned short*)alloc((size_t)512*HCDIM*2);
    unsigned short* Pe  = (unsigned short*)alloc((size_t)N*CH*2);

    // preprocessing (+ both weight conversions upfront)
    k_init<<<(N+255)/256, 256, 0, stream>>>(deg, lsum, cursor, N);
    k_count<<<(E+255)/256, 256, 0, stream>>>(dst0, eattr, deg, lsum, E);
    k_scan<<<1, 1024, 0, stream>>>(deg, offs, N);
    k_loopattr<<<(N+255)/256, 256, 0, stream>>>(deg, lsum, lattr, N);
    k_scatter<<<(E+255)/256, 256, 0, stream>>>(src0, dst0, eattr, offs, cursor, csr, E);
    k_cvtw2<<<1024, 256, 0, stream>>>(Wl[1], Wr[1], Wl[2], Wr[2], Wt1, Wt2);

    int gat_grid  = (N + 1) / 2;     // 2 nodes per block, 2 waves per node
    dim3 mfma_grid((N + BM - 1) / BM, 4);

    // layer 0 (din=3, fp32 vector GEMM -> bf16 xl/xr)
    k_dualgemm<<<(N+15)/16, 256, 0, stream>>>(x, 3, Wl[0], bl[0], Wr[0], br[0], XL, XR, N);
    k_gat<<<gat_grid, 256, 0, stream>>>(XL, XR, csr, offs, lattr,
                                        We[0], att[0], bias[0], Hb, nullptr, N, 1);
    // layer 1 (din=256, bf16 MFMA)
    k_mfma_gemm<<<mfma_grid, 256, 0, stream>>>(Hb, Wt1, bl[1], br[1], XL, XR, N);
    k_gat<<<gat_grid, 256, 0, stream>>>(XL, XR, csr, offs, lattr,
                                        We[1], att[1], bias[1], Hb, nullptr, N, 1);
    // layer 2 (din=256, bf16 MFMA, concat=false -> f32 N x 32)
    k_mfma_gemm<<<mfma_grid, 256, 0, stream>>>(Hb, Wt2, bl[2], br[2], XL, XR, N);
    k_gat<<<gat_grid, 256, 0, stream>>>(XL, XR, csr, offs, lattr,
                                        We[2], att[2], bias[2], nullptr, H0f, N, 0);

    // fused node head + edge-P precompute, then tiny per-edge finisher
    float* out_node = (float*)d_out;
    float* out_edge = out_node + (size_t)N*2;
    k_heads<<<(N+7)/8, 256, 0, stream>>>(H0f, nhW1, nhb1, nhW2, nhb2, ehW1,
                                         out_node, Pe, N);
    k_edgefin<<<((size_t)E*8 + 255)/256, 256, 0, stream>>>(Pe, src0, dst0,
                                                           ehb1, ehW2, ehb2, out_edge, E);
}